// Round 11
// baseline (558.776 us; speedup 1.0000x reference)
//
#include <hip/hip_runtime.h>

#define NN 100000
#define NE 3200000
#define FIN 256
#define H1 8
#define C2 16
#define NEG 0.2f

#define BKT 64                        // dst nodes per fine bucket
#define NB 1563                       // fine buckets with real nodes
#define NBP 1568                      // padded fine buckets (32 supers * 49)
#define CAP 2560                      // max edges per fine bucket (mean 2048)
#define SB 32                         // super-buckets
#define SBN 3136                      // nodes per super (49 * 64)
#define FPS 49                        // fine buckets per super
#define SCAP 110000                   // super region capacity (mean 100352)
#define P1B 1024                      // partition-1 logical blocks
#define EPB1 3125                     // NE / P1B
#define LINB 1563                     // lin logical blocks (64 nodes each)
#define P2CAP 3520                    // >= max super slice
#define XR 132                        // x-tile row stride

// ---- fused front kernel: role by blockIdx%5 (3 lin : 2 p1) ----
__global__ __launch_bounds__(512) void k_b(
        const float* __restrict__ x,
        const float* __restrict__ Wl, const float* __restrict__ bl,
        const float* __restrict__ Wr, const float* __restrict__ br,
        float* __restrict__ xl1, float* __restrict__ xr1,
        const int* __restrict__ ei,
        int* __restrict__ gcur1, int* __restrict__ sup1) {
    __shared__ int smem[10240];        // 40 KB shared by both roles
    int tid = threadIdx.x;
    int m = blockIdx.x % 5, d = blockIdx.x / 5;

    if (m >= 3) {
        // ---------------- partition stage 1 ----------------
        int p1 = d * 2 + (m - 3);
        if (p1 >= P1B) return;
        int* buf  = smem;              // EPB1
        int* cnt  = smem + EPB1;
        int* nb   = cnt + SB;
        int* cnt2 = nb + SB;
        int* gb   = cnt2 + SB;
        int base = p1 * EPB1;
        if (tid < SB) { cnt[tid] = 0; cnt2[tid] = 0; }
        int es[7], ed[7];
        #pragma unroll
        for (int r = 0; r < 7; ++r) {
            int i = tid + r * 512;
            if (i < EPB1) { es[r] = ei[base + i]; ed[r] = ei[NE + base + i]; }
        }
        __syncthreads();
        #pragma unroll
        for (int r = 0; r < 7; ++r) {
            int i = tid + r * 512;
            if (i < EPB1) atomicAdd(&cnt[ed[r] / SBN], 1);
        }
        __syncthreads();
        if (tid < SB) {                // scan + global reserve
            int v = cnt[tid], inc = v;
            #pragma unroll
            for (int off = 1; off < SB; off <<= 1) {
                int u = __shfl_up(inc, off, 64);
                if (tid >= off) inc += u;
            }
            nb[tid] = inc - v;
            gb[tid] = atomicAdd(&gcur1[tid], v);
        }
        __syncthreads();
        #pragma unroll
        for (int r = 0; r < 7; ++r) {
            int i = tid + r * 512;
            if (i < EPB1) {
                int s = ed[r] / SBN;
                int rr = ed[r] - s * SBN;
                int k = atomicAdd(&cnt2[s], 1);
                buf[nb[s] + k] = (rr << 17) | es[r];
            }
        }
        __syncthreads();
        for (int s = 0; s < SB; ++s) { // coalesced run flush
            int c = cnt[s], b = gb[s], o = nb[s];
            size_t dbase = (size_t)s * SCAP + b;
            for (int i = tid; i < c; i += 512)
                if (b + i < SCAP) sup1[dbase + i] = buf[o + i];
        }
    } else {
        // ---- layer-1 linear: x tile in LDS (coalesced), weights via s_load
        int lb = d * 3 + m;            // 0..1562
        int blkNode = lb * 64;
        float* xf   = (float*)smem;    // [64][XR]
        float* part = (float*)smem;    // reuse: [8][64][20]
        int lane = tid & 63;
        int wq = __builtin_amdgcn_readfirstlane(tid >> 6);   // k-sixteenth 0..7

        float accl[8] = {0,0,0,0,0,0,0,0}, accr[8] = {0,0,0,0,0,0,0,0};

        #pragma unroll
        for (int ph = 0; ph < 2; ++ph) {
            __syncthreads();
            #pragma unroll
            for (int pass = 0; pass < 4; ++pass) {
                int i = tid + pass * 512;      // float4 index, 2048 total
                int row = i >> 5, c4 = i & 31;
                int node = blkNode + row; if (node >= NN) node = NN - 1;
                float4 v = *(const float4*)(x + (size_t)node * FIN + ph * 128 + c4 * 4);
                *(float4*)&xf[row * XR + c4 * 4] = v;
            }
            __syncthreads();
            int kbase = ph * 128 + wq * 16;
            const float* wlp = Wl + kbase * 8;     // scalar (wave-uniform)
            const float* wrp = Wr + kbase * 8;
            const float* xrow = &xf[lane * XR + wq * 16];
            #pragma unroll
            for (int jq = 0; jq < 4; ++jq) {
                float4 xv = *(const float4*)(xrow + jq * 4);
                float xa[4] = {xv.x, xv.y, xv.z, xv.w};
                #pragma unroll
                for (int r = 0; r < 4; ++r) {
                    int k = jq * 4 + r;
                    #pragma unroll
                    for (int h = 0; h < 8; ++h) {
                        accl[h] = fmaf(xa[r], wlp[k * 8 + h], accl[h]);
                        accr[h] = fmaf(xa[r], wrp[k * 8 + h], accr[h]);
                    }
                }
            }
        }
        __syncthreads();
        float* pw = part + (size_t)(wq * 64 + lane) * 20;
        *(float4*)(pw)      = make_float4(accl[0], accl[1], accl[2], accl[3]);
        *(float4*)(pw + 4)  = make_float4(accl[4], accl[5], accl[6], accl[7]);
        *(float4*)(pw + 8)  = make_float4(accr[0], accr[1], accr[2], accr[3]);
        *(float4*)(pw + 12) = make_float4(accr[4], accr[5], accr[6], accr[7]);
        __syncthreads();
        int n2 = tid >> 3, p = tid & 7;
        float s0 = 0.f, s1 = 0.f;
        #pragma unroll
        for (int w2 = 0; w2 < 8; ++w2) {
            const float* pr = part + (size_t)(w2 * 64 + n2) * 20 + p * 2;
            s0 += pr[0]; s1 += pr[1];
        }
        int node = blkNode + n2;
        if (node < NN) {
            int o = p * 2;
            if (o < 8) {
                s0 += bl[o]; s1 += bl[o + 1];
                *(float2*)(xl1 + (size_t)node * H1 + o) = make_float2(s0, s1);
            } else {
                s0 += br[o - 8]; s1 += br[o - 7];
                *(float2*)(xr1 + (size_t)node * H1 + (o - 8)) = make_float2(s0, s1);
            }
        }
    }
}

// ---- partition stage 2: super slice -> 49 fine buckets (32 slices/super) ---
__global__ __launch_bounds__(512) void k_p2(const int* __restrict__ sup1,
                                            const int* __restrict__ gcur1,
                                            int* __restrict__ gcur2,
                                            int* __restrict__ bedges) {
    __shared__ int buf[P2CAP];
    __shared__ int cnt[FPS], nb[FPS], cnt2[FPS], gb[FPS];
    int s   = blockIdx.x >> 5;
    int sub = blockIdx.x & 31;
    int tid = threadIdx.x;
    int total = gcur1[s]; if (total > SCAP) total = SCAP;
    int beg = (int)((long)total * sub / 32);
    int end = (int)((long)total * (sub + 1) / 32);
    int n = end - beg;
    const int* sp = sup1 + (size_t)s * SCAP + beg;
    if (tid < FPS) { cnt[tid] = 0; cnt2[tid] = 0; }
    int pk[7];
    #pragma unroll
    for (int r = 0; r < 7; ++r) {
        int i = tid + r * 512;
        if (i < n) pk[r] = sp[i];
    }
    __syncthreads();
    #pragma unroll
    for (int r = 0; r < 7; ++r) {
        int i = tid + r * 512;
        if (i < n) atomicAdd(&cnt[(pk[r] >> 17) >> 6], 1);
    }
    __syncthreads();
    if (tid < 64) {
        int v = (tid < FPS) ? cnt[tid] : 0, inc = v;
        #pragma unroll
        for (int off = 1; off < 64; off <<= 1) {
            int u = __shfl_up(inc, off, 64);
            if (tid >= off) inc += u;
        }
        if (tid < FPS) {
            nb[tid] = inc - v;
            gb[tid] = atomicAdd(&gcur2[s * FPS + tid], v);
        }
    }
    __syncthreads();
    #pragma unroll
    for (int r = 0; r < 7; ++r) {
        int i = tid + r * 512;
        if (i < n) {
            int fb = (pk[r] >> 17) >> 6;
            int k = atomicAdd(&cnt2[fb], 1);
            buf[nb[fb] + k] = (((pk[r] >> 17) & 63) << 17) | (pk[r] & 0x1FFFF);
        }
    }
    __syncthreads();
    for (int fb = 0; fb < FPS; ++fb) {
        int c = cnt[fb], b = gb[fb], o = nb[fb];
        size_t dbase = (size_t)(s * FPS + fb) * CAP + b;
        for (int i = tid; i < c; i += 512)
            if (b + i < CAP) bedges[dbase + i] = buf[o + i];
    }
}

// ---- GAT layer 1 (D=8), edge-parallel with LDS atomic accumulators,
//      fused mid GEMM epilogue ----
__global__ __launch_bounds__(512) void k_ag1(
        const int* __restrict__ bedges, const int* __restrict__ gcur2,
        const float* __restrict__ xl, const float* __restrict__ xr,
        const float* __restrict__ att, const float* __restrict__ bias,
        const float* __restrict__ Wl2, const float* __restrict__ bl2,
        const float* __restrict__ Wr2, const float* __restrict__ br2,
        float* __restrict__ xl2, float* __restrict__ xr2) {
    __shared__ float nacc[BKT * 13];   // per node: acc[0..7], denom[8]; stride 13 (odd)
    int bkt = blockIdx.x;
    int tid = threadIdx.x;
    int ecnt = gcur2[bkt]; if (ecnt > CAP) ecnt = CAP;
    for (int i = tid; i < BKT * 13; i += 512) nacc[i] = 0.f;
    float attv[8];
    #pragma unroll
    for (int d2 = 0; d2 < 8; ++d2) attv[d2] = att[d2];
    __syncthreads();

    const int* be = bedges + (size_t)bkt * CAP;
    int ntot = ecnt + BKT;             // + synthetic self-loop edges
    for (int i = tid; i < ntot; i += 512) {
        int dl, src;
        if (i < ecnt) { int pk = be[i]; dl = pk >> 17; src = pk & 0x1FFFF; }
        else { dl = i - ecnt; src = bkt * BKT + dl; if (src >= NN) continue; }
        int g = bkt * BKT + dl;
        float4 a0 = *(const float4*)(xl + (size_t)src * H1);
        float4 a1 = *(const float4*)(xl + (size_t)src * H1 + 4);
        float4 b0 = *(const float4*)(xr + (size_t)g * H1);
        float4 b1 = *(const float4*)(xr + (size_t)g * H1 + 4);
        float xv[8] = {a0.x, a0.y, a0.z, a0.w, a1.x, a1.y, a1.z, a1.w};
        float rv[8] = {b0.x, b0.y, b0.z, b0.w, b1.x, b1.y, b1.z, b1.w};
        float s = 0.f;
        #pragma unroll
        for (int d2 = 0; d2 < 8; ++d2) {
            float w = xv[d2] + rv[d2];
            w = fmaxf(w, NEG * w);
            s = fmaf(attv[d2], w, s);
        }
        float ex = __expf(s);
        float* np = &nacc[dl * 13];
        #pragma unroll
        for (int d2 = 0; d2 < 8; ++d2)
            atomicAdd(np + d2, ex * xv[d2]);
        atomicAdd(np + 8, ex);
    }
    __syncthreads();

    // epilogue: 8 threads per node; thread covers output pair (2p, 2p+1)
    int n = tid >> 3, p = tid & 7;
    int g = bkt * BKT + n;
    if (g < NN) {
        const float* np = &nacc[n * 13];
        float inv = 1.f / np[8];
        float h[8];
        #pragma unroll
        for (int d2 = 0; d2 < 8; ++d2)
            h[d2] = fmaxf(np[d2] * inv + bias[d2], 0.f);
        int c0 = p * 2;
        float al0 = bl2[c0], al1 = bl2[c0 + 1];
        float ar0 = br2[c0], ar1 = br2[c0 + 1];
        #pragma unroll
        for (int d2 = 0; d2 < 8; ++d2) {
            al0 = fmaf(h[d2], Wl2[d2 * C2 + c0],     al0);
            al1 = fmaf(h[d2], Wl2[d2 * C2 + c0 + 1], al1);
            ar0 = fmaf(h[d2], Wr2[d2 * C2 + c0],     ar0);
            ar1 = fmaf(h[d2], Wr2[d2 * C2 + c0 + 1], ar1);
        }
        *(float2*)(xl2 + (size_t)g * C2 + c0) = make_float2(al0, al1);
        *(float2*)(xr2 + (size_t)g * C2 + c0) = make_float2(ar0, ar1);
    }
}

// ---- GAT layer 2 (D=16), edge-parallel with LDS atomic accumulators ----
__global__ __launch_bounds__(512) void k_ag2(
        const int* __restrict__ bedges, const int* __restrict__ gcur2,
        const float* __restrict__ xl, const float* __restrict__ xr,
        const float* __restrict__ att, const float* __restrict__ bias,
        float* __restrict__ out) {
    __shared__ float nacc[BKT * 17];   // per node: acc[0..15], denom[16]; stride 17
    int bkt = blockIdx.x;
    int tid = threadIdx.x;
    int ecnt = gcur2[bkt]; if (ecnt > CAP) ecnt = CAP;
    for (int i = tid; i < BKT * 17; i += 512) nacc[i] = 0.f;
    float attv[16];
    #pragma unroll
    for (int d2 = 0; d2 < 16; ++d2) attv[d2] = att[d2];
    __syncthreads();

    const int* be = bedges + (size_t)bkt * CAP;
    int ntot = ecnt + BKT;
    for (int i = tid; i < ntot; i += 512) {
        int dl, src;
        if (i < ecnt) { int pk = be[i]; dl = pk >> 17; src = pk & 0x1FFFF; }
        else { dl = i - ecnt; src = bkt * BKT + dl; if (src >= NN) continue; }
        int g = bkt * BKT + dl;
        float xv[16], rv[16];
        #pragma unroll
        for (int q4 = 0; q4 < 4; ++q4) {
            float4 a = *(const float4*)(xl + (size_t)src * C2 + q4 * 4);
            float4 b = *(const float4*)(xr + (size_t)g * C2 + q4 * 4);
            xv[q4 * 4 + 0] = a.x; xv[q4 * 4 + 1] = a.y;
            xv[q4 * 4 + 2] = a.z; xv[q4 * 4 + 3] = a.w;
            rv[q4 * 4 + 0] = b.x; rv[q4 * 4 + 1] = b.y;
            rv[q4 * 4 + 2] = b.z; rv[q4 * 4 + 3] = b.w;
        }
        float s = 0.f;
        #pragma unroll
        for (int d2 = 0; d2 < 16; ++d2) {
            float w = xv[d2] + rv[d2];
            w = fmaxf(w, NEG * w);
            s = fmaf(attv[d2], w, s);
        }
        float ex = __expf(s);
        float* np = &nacc[dl * 17];
        #pragma unroll
        for (int d2 = 0; d2 < 16; ++d2)
            atomicAdd(np + d2, ex * xv[d2]);
        atomicAdd(np + 16, ex);
    }
    __syncthreads();

    // epilogue: 8 threads per node; thread covers outputs (2p, 2p+1)
    int n = tid >> 3, p = tid & 7;
    int g = bkt * BKT + n;
    if (g < NN) {
        const float* np = &nacc[n * 17];
        float inv = 1.f / np[16];
        int c0 = p * 2;
        float2 r;
        r.x = np[c0]     * inv + bias[c0];
        r.y = np[c0 + 1] * inv + bias[c0 + 1];
        *(float2*)(out + (size_t)g * C2 + c0) = r;
    }
}

extern "C" void kernel_launch(void* const* d_in, const int* in_sizes, int n_in,
                              void* d_out, int out_size, void* d_ws, size_t ws_size,
                              hipStream_t stream) {
    const float* x     = (const float*)d_in[0];
    const int*   ei    = (const int*)d_in[1];
    const float* Wl1   = (const float*)d_in[2];
    const float* bl1   = (const float*)d_in[3];
    const float* Wr1   = (const float*)d_in[4];
    const float* br1   = (const float*)d_in[5];
    const float* att1  = (const float*)d_in[6];
    const float* bias1 = (const float*)d_in[7];
    const float* Wl2   = (const float*)d_in[8];
    const float* bl2   = (const float*)d_in[9];
    const float* Wr2   = (const float*)d_in[10];
    const float* br2   = (const float*)d_in[11];
    const float* att2  = (const float*)d_in[12];
    const float* bias2 = (const float*)d_in[13];
    float* out = (float*)d_out;

    // workspace layout
    int* bedges = (int*)d_ws;                        // NBP*CAP
    int* gcur1  = bedges + (size_t)NBP * CAP;        // 32
    int* gcur2  = gcur1 + SB;                        // NBP
    float* xl1  = (float*)(gcur2 + NBP);             // NN*H1
    float* xr1  = xl1 + (size_t)NN * H1;             // NN*H1
    int* sup1   = (int*)(xr1 + (size_t)NN * H1);     // SB*SCAP (14.08 MB)
    float* xl2  = (float*)sup1;                      // overlay: sup1 dead after k_p2
    float* xr2  = xl2 + (size_t)NN * C2;             // NN*C2

    hipMemsetAsync(gcur1, 0, (SB + NBP) * sizeof(int), stream);

    k_b<<<2605, 512, 0, stream>>>(x, Wl1, bl1, Wr1, br1, xl1, xr1,
                                  ei, gcur1, sup1);
    k_p2<<<1024, 512, 0, stream>>>(sup1, gcur1, gcur2, bedges);
    k_ag1<<<NB, 512, 0, stream>>>(bedges, gcur2, xl1, xr1, att1, bias1,
                                  Wl2, bl2, Wr2, br2, xl2, xr2);
    k_ag2<<<NB, 512, 0, stream>>>(bedges, gcur2, xl2, xr2, att2, bias2, out);
}

// Round 12
// 164.726 us; speedup vs baseline: 3.3921x; 3.3921x over previous
//
#include <hip/hip_runtime.h>

#define NN 100000
#define NE 3200000
#define FIN 256
#define H1 8
#define C2 16
#define NEG 0.2f

#define BKT 64                        // dst nodes per fine bucket
#define NB 1563                       // fine buckets with real nodes
#define NBP 1568                      // padded fine buckets (32 supers * 49)
#define CAP 2560                      // max edges per fine bucket (mean 2048)
#define SB 32                         // super-buckets
#define SBN 3136                      // nodes per super (49 * 64)
#define FPS 49                        // fine buckets per super
#define SCAP 110000                   // super region capacity (mean 100352)
#define P1B 1024                      // partition-1 logical blocks
#define EPB1 3125                     // NE / P1B
#define LINB 1563                     // lin logical blocks (64 nodes each)
#define P2CAP 3520                    // >= max super slice
#define XR 132                        // x-tile row stride

// ---- tiny clear kernel (replaces hipMemsetAsync graph node) ----
__global__ __launch_bounds__(512) void k_clr(int* __restrict__ g) {
    int i = blockIdx.x * 512 + threadIdx.x;
    if (i < SB + NBP) g[i] = 0;
}

// ---- fused front kernel: role by blockIdx%5 (3 lin : 2 p1) ----
__global__ __launch_bounds__(512) void k_b(
        const float* __restrict__ x,
        const float* __restrict__ Wl, const float* __restrict__ bl,
        const float* __restrict__ Wr, const float* __restrict__ br,
        float* __restrict__ xl1, float* __restrict__ xr1,
        const int* __restrict__ ei,
        int* __restrict__ gcur1, int* __restrict__ sup1) {
    __shared__ int smem[10240];        // 40 KB shared by both roles
    int tid = threadIdx.x;
    int m = blockIdx.x % 5, d = blockIdx.x / 5;

    if (m >= 3) {
        // ---------------- partition stage 1 ----------------
        int p1 = d * 2 + (m - 3);
        if (p1 >= P1B) return;
        int* buf  = smem;              // EPB1
        int* cnt  = smem + EPB1;
        int* nb   = cnt + SB;
        int* cnt2 = nb + SB;
        int* gb   = cnt2 + SB;
        int base = p1 * EPB1;
        if (tid < SB) { cnt[tid] = 0; cnt2[tid] = 0; }
        int es[7], ed[7];
        #pragma unroll
        for (int r = 0; r < 7; ++r) {
            int i = tid + r * 512;
            if (i < EPB1) { es[r] = ei[base + i]; ed[r] = ei[NE + base + i]; }
        }
        __syncthreads();
        #pragma unroll
        for (int r = 0; r < 7; ++r) {
            int i = tid + r * 512;
            if (i < EPB1) atomicAdd(&cnt[ed[r] / SBN], 1);
        }
        __syncthreads();
        if (tid < SB) {                // scan + global reserve
            int v = cnt[tid], inc = v;
            #pragma unroll
            for (int off = 1; off < SB; off <<= 1) {
                int u = __shfl_up(inc, off, 64);
                if (tid >= off) inc += u;
            }
            nb[tid] = inc - v;
            gb[tid] = atomicAdd(&gcur1[tid], v);
        }
        __syncthreads();
        #pragma unroll
        for (int r = 0; r < 7; ++r) {
            int i = tid + r * 512;
            if (i < EPB1) {
                int s = ed[r] / SBN;
                int rr = ed[r] - s * SBN;
                int k = atomicAdd(&cnt2[s], 1);
                buf[nb[s] + k] = (rr << 17) | es[r];
            }
        }
        __syncthreads();
        for (int s = 0; s < SB; ++s) { // coalesced run flush
            int c = cnt[s], b = gb[s], o = nb[s];
            size_t dbase = (size_t)s * SCAP + b;
            for (int i = tid; i < c; i += 512)
                if (b + i < SCAP) sup1[dbase + i] = buf[o + i];
        }
    } else {
        // ---- layer-1 linear: x tile in LDS (coalesced), weights via s_load
        int lb = d * 3 + m;            // 0..1562
        int blkNode = lb * 64;
        float* xf   = (float*)smem;    // [64][XR]
        float* part = (float*)smem;    // reuse: [8][64][20]
        int lane = tid & 63;
        int wq = __builtin_amdgcn_readfirstlane(tid >> 6);   // k-sixteenth 0..7

        float accl[8] = {0,0,0,0,0,0,0,0}, accr[8] = {0,0,0,0,0,0,0,0};

        #pragma unroll
        for (int ph = 0; ph < 2; ++ph) {
            __syncthreads();
            #pragma unroll
            for (int pass = 0; pass < 4; ++pass) {
                int i = tid + pass * 512;      // float4 index, 2048 total
                int row = i >> 5, c4 = i & 31;
                int node = blkNode + row; if (node >= NN) node = NN - 1;
                float4 v = *(const float4*)(x + (size_t)node * FIN + ph * 128 + c4 * 4);
                *(float4*)&xf[row * XR + c4 * 4] = v;
            }
            __syncthreads();
            int kbase = ph * 128 + wq * 16;
            const float* wlp = Wl + kbase * 8;     // scalar (wave-uniform)
            const float* wrp = Wr + kbase * 8;
            const float* xrow = &xf[lane * XR + wq * 16];
            #pragma unroll
            for (int jq = 0; jq < 4; ++jq) {
                float4 xv = *(const float4*)(xrow + jq * 4);
                float xa[4] = {xv.x, xv.y, xv.z, xv.w};
                #pragma unroll
                for (int r = 0; r < 4; ++r) {
                    int k = jq * 4 + r;
                    #pragma unroll
                    for (int h = 0; h < 8; ++h) {
                        accl[h] = fmaf(xa[r], wlp[k * 8 + h], accl[h]);
                        accr[h] = fmaf(xa[r], wrp[k * 8 + h], accr[h]);
                    }
                }
            }
        }
        __syncthreads();
        float* pw = part + (size_t)(wq * 64 + lane) * 20;
        *(float4*)(pw)      = make_float4(accl[0], accl[1], accl[2], accl[3]);
        *(float4*)(pw + 4)  = make_float4(accl[4], accl[5], accl[6], accl[7]);
        *(float4*)(pw + 8)  = make_float4(accr[0], accr[1], accr[2], accr[3]);
        *(float4*)(pw + 12) = make_float4(accr[4], accr[5], accr[6], accr[7]);
        __syncthreads();
        int n2 = tid >> 3, p = tid & 7;
        float s0 = 0.f, s1 = 0.f;
        #pragma unroll
        for (int w2 = 0; w2 < 8; ++w2) {
            const float* pr = part + (size_t)(w2 * 64 + n2) * 20 + p * 2;
            s0 += pr[0]; s1 += pr[1];
        }
        int node = blkNode + n2;
        if (node < NN) {
            int o = p * 2;
            if (o < 8) {
                s0 += bl[o]; s1 += bl[o + 1];
                *(float2*)(xl1 + (size_t)node * H1 + o) = make_float2(s0, s1);
            } else {
                s0 += br[o - 8]; s1 += br[o - 7];
                *(float2*)(xr1 + (size_t)node * H1 + (o - 8)) = make_float2(s0, s1);
            }
        }
    }
}

// ---- partition stage 2: super slice -> 49 fine buckets (32 slices/super) ---
__global__ __launch_bounds__(512) void k_p2(const int* __restrict__ sup1,
                                            const int* __restrict__ gcur1,
                                            int* __restrict__ gcur2,
                                            int* __restrict__ bedges) {
    __shared__ int buf[P2CAP];
    __shared__ int cnt[FPS], nb[FPS], cnt2[FPS], gb[FPS];
    int s   = blockIdx.x >> 5;
    int sub = blockIdx.x & 31;
    int tid = threadIdx.x;
    int total = gcur1[s]; if (total > SCAP) total = SCAP;
    int beg = (int)((long)total * sub / 32);
    int end = (int)((long)total * (sub + 1) / 32);
    int n = end - beg;
    const int* sp = sup1 + (size_t)s * SCAP + beg;
    if (tid < FPS) { cnt[tid] = 0; cnt2[tid] = 0; }
    int pk[7];
    #pragma unroll
    for (int r = 0; r < 7; ++r) {
        int i = tid + r * 512;
        if (i < n) pk[r] = sp[i];
    }
    __syncthreads();
    #pragma unroll
    for (int r = 0; r < 7; ++r) {
        int i = tid + r * 512;
        if (i < n) atomicAdd(&cnt[(pk[r] >> 17) >> 6], 1);
    }
    __syncthreads();
    if (tid < 64) {
        int v = (tid < FPS) ? cnt[tid] : 0, inc = v;
        #pragma unroll
        for (int off = 1; off < 64; off <<= 1) {
            int u = __shfl_up(inc, off, 64);
            if (tid >= off) inc += u;
        }
        if (tid < FPS) {
            nb[tid] = inc - v;
            gb[tid] = atomicAdd(&gcur2[s * FPS + tid], v);
        }
    }
    __syncthreads();
    #pragma unroll
    for (int r = 0; r < 7; ++r) {
        int i = tid + r * 512;
        if (i < n) {
            int fb = (pk[r] >> 17) >> 6;
            int k = atomicAdd(&cnt2[fb], 1);
            buf[nb[fb] + k] = (((pk[r] >> 17) & 63) << 17) | (pk[r] & 0x1FFFF);
        }
    }
    __syncthreads();
    for (int fb = 0; fb < FPS; ++fb) {
        int c = cnt[fb], b = gb[fb], o = nb[fb];
        size_t dbase = (size_t)(s * FPS + fb) * CAP + b;
        for (int i = tid; i < c; i += 512)
            if (b + i < CAP) bedges[dbase + i] = buf[o + i];
    }
}

// ---- fused: per-bucket counting sort + layer-1 GAT (dual-node ILP) + mid GEMM
__global__ __launch_bounds__(512) void k_sortgat1(
        int* __restrict__ bedges, const int* __restrict__ gcur2,
        int* __restrict__ meta,
        const float* __restrict__ xl, const float* __restrict__ xr,
        const float* __restrict__ att, const float* __restrict__ bias,
        const float* __restrict__ Wl2, const float* __restrict__ bl2,
        const float* __restrict__ Wr2, const float* __restrict__ br2,
        float* __restrict__ xl2, float* __restrict__ xr2) {
    __shared__ int sorted[CAP];
    __shared__ int hist[BKT], nbase[BKT], scnt[BKT];
    int bkt = blockIdx.x;
    int tid = threadIdx.x;
    int ecnt = gcur2[bkt]; if (ecnt > CAP) ecnt = CAP;
    int* be = bedges + (size_t)bkt * CAP;
    if (tid < BKT) { hist[tid] = 0; scnt[tid] = 0; }
    __syncthreads();
    for (int i = tid; i < ecnt; i += 512)
        atomicAdd(&hist[be[i] >> 17], 1);
    __syncthreads();
    if (tid < BKT) {                   // wave-parallel exclusive scan
        int v = hist[tid], inc = v;
        #pragma unroll
        for (int off = 1; off < 64; off <<= 1) {
            int u = __shfl_up(inc, off, 64);
            if (tid >= off) inc += u;
        }
        nbase[tid] = inc - v;
        meta[bkt * BKT + tid] = ((inc - v) << 16) | v;   // for layer 2
    }
    __syncthreads();
    for (int i = tid; i < ecnt; i += 512) {
        int pk = be[i];
        int dl = pk >> 17;
        int r = atomicAdd(&scnt[dl], 1);
        sorted[nbase[dl] + r] = pk & 0x1FFFF;
    }
    __syncthreads();
    for (int i = tid; i < ecnt; i += 512)   // writeback for layer 2
        be[i] = sorted[i];

    // -------- layer-1 GAT (D=8), two nodes (n, n+32) per iteration --------
    int wave = tid >> 6, lane = tid & 63;
    int q = lane & 1, eo = lane >> 1;       // LPE=2, EPC=32

    float attq[4], biasq[4];
    #pragma unroll
    for (int j = 0; j < 4; ++j) { attq[j] = att[q * 4 + j]; biasq[j] = bias[q * 4 + j]; }
    float wl2c[H1], wr2c[H1], bl2c = 0.f, br2c = 0.f;
    if (lane < C2) {
        #pragma unroll
        for (int d = 0; d < H1; ++d) {
            wl2c[d] = Wl2[d * C2 + lane];
            wr2c[d] = Wr2[d * C2 + lane];
        }
        bl2c = bl2[lane]; br2c = br2[lane];
    }

    for (int n = wave; n < 32; n += 8) {
        int nA = n, nB = n + 32;
        int gA = bkt * BKT + nA, gB = bkt * BKT + nB;
        int gAc = gA < NN ? gA : NN - 1;
        int gBc = gB < NN ? gB : NN - 1;
        int degA = hist[nA] + 1, degB = hist[nB] + 1;
        int nbA = nbase[nA], nbB = nbase[nB];

        float4 xrA = ((const float4*)(xr + (size_t)gAc * H1))[q];
        float4 xrB = ((const float4*)(xr + (size_t)gBc * H1))[q];
        float xrAq[4] = {xrA.x, xrA.y, xrA.z, xrA.w};
        float xrBq[4] = {xrB.x, xrB.y, xrB.z, xrB.w};

        // chunk 0 of both nodes: both gathers issued before any compute
        int srcA = (eo > 0 && eo < degA) ? sorted[nbA + eo - 1] : gAc;
        int srcB = (eo > 0 && eo < degB) ? sorted[nbB + eo - 1] : gBc;
        float4 vA = ((const float4*)(xl + (size_t)srcA * H1))[q];
        float4 vB = ((const float4*)(xl + (size_t)srcB * H1))[q];

        float denA, denB, accA[4], accB[4];
        {
            float xa[4] = {vA.x, vA.y, vA.z, vA.w};
            float xb[4] = {vB.x, vB.y, vB.z, vB.w};
            float sA = 0.f, sB = 0.f;
            #pragma unroll
            for (int j = 0; j < 4; ++j) {
                float wa = xa[j] + xrAq[j]; wa = fmaxf(wa, NEG * wa);
                float wb = xb[j] + xrBq[j]; wb = fmaxf(wb, NEG * wb);
                sA = fmaf(attq[j], wa, sA);
                sB = fmaf(attq[j], wb, sB);
            }
            sA += __shfl_xor(sA, 1, 64);
            sB += __shfl_xor(sB, 1, 64);
            float exA = (eo < degA) ? __expf(sA) : 0.f;
            float exB = (eo < degB) ? __expf(sB) : 0.f;
            denA = exA; denB = exB;
            #pragma unroll
            for (int j = 0; j < 4; ++j) { accA[j] = exA * xa[j]; accB[j] = exB * xb[j]; }
        }
        // chunk 1 (32..63), per node, wave-uniform guards
        if (degA > 32) {
            int e = 32 + eo;
            int src = (e < degA) ? sorted[nbA + e - 1] : gAc;
            float4 v = ((const float4*)(xl + (size_t)src * H1))[q];
            float xa[4] = {v.x, v.y, v.z, v.w};
            float s = 0.f;
            #pragma unroll
            for (int j = 0; j < 4; ++j) {
                float w = xa[j] + xrAq[j]; w = fmaxf(w, NEG * w);
                s = fmaf(attq[j], w, s);
            }
            s += __shfl_xor(s, 1, 64);
            float ex = (e < degA) ? __expf(s) : 0.f;
            denA += ex;
            #pragma unroll
            for (int j = 0; j < 4; ++j) accA[j] = fmaf(ex, xa[j], accA[j]);
        }
        if (degB > 32) {
            int e = 32 + eo;
            int src = (e < degB) ? sorted[nbB + e - 1] : gBc;
            float4 v = ((const float4*)(xl + (size_t)src * H1))[q];
            float xb[4] = {v.x, v.y, v.z, v.w};
            float s = 0.f;
            #pragma unroll
            for (int j = 0; j < 4; ++j) {
                float w = xb[j] + xrBq[j]; w = fmaxf(w, NEG * w);
                s = fmaf(attq[j], w, s);
            }
            s += __shfl_xor(s, 1, 64);
            float ex = (e < degB) ? __expf(s) : 0.f;
            denB += ex;
            #pragma unroll
            for (int j = 0; j < 4; ++j) accB[j] = fmaf(ex, xb[j], accB[j]);
        }
        // rare: deg > 64
        for (int e0 = 64; e0 < degA; e0 += 32) {
            int e = e0 + eo;
            int src = (e < degA) ? sorted[nbA + e - 1] : gAc;
            float4 v = ((const float4*)(xl + (size_t)src * H1))[q];
            float xa[4] = {v.x, v.y, v.z, v.w};
            float s = 0.f;
            #pragma unroll
            for (int j = 0; j < 4; ++j) {
                float w = xa[j] + xrAq[j]; w = fmaxf(w, NEG * w);
                s = fmaf(attq[j], w, s);
            }
            s += __shfl_xor(s, 1, 64);
            float ex = (e < degA) ? __expf(s) : 0.f;
            denA += ex;
            #pragma unroll
            for (int j = 0; j < 4; ++j) accA[j] = fmaf(ex, xa[j], accA[j]);
        }
        for (int e0 = 64; e0 < degB; e0 += 32) {
            int e = e0 + eo;
            int src = (e < degB) ? sorted[nbB + e - 1] : gBc;
            float4 v = ((const float4*)(xl + (size_t)src * H1))[q];
            float xb[4] = {v.x, v.y, v.z, v.w};
            float s = 0.f;
            #pragma unroll
            for (int j = 0; j < 4; ++j) {
                float w = xb[j] + xrBq[j]; w = fmaxf(w, NEG * w);
                s = fmaf(attq[j], w, s);
            }
            s += __shfl_xor(s, 1, 64);
            float ex = (e < degB) ? __expf(s) : 0.f;
            denB += ex;
            #pragma unroll
            for (int j = 0; j < 4; ++j) accB[j] = fmaf(ex, xb[j], accB[j]);
        }
        // cross-edge butterflies, both nodes interleaved
        #pragma unroll
        for (int off = 2; off < 64; off <<= 1) {
            denA += __shfl_xor(denA, off, 64);
            denB += __shfl_xor(denB, off, 64);
            #pragma unroll
            for (int j = 0; j < 4; ++j) {
                accA[j] += __shfl_xor(accA[j], off, 64);
                accB[j] += __shfl_xor(accB[j], off, 64);
            }
        }
        float invA = 1.f / denA, invB = 1.f / denB;

        // epilogue both nodes: relu + mid GEMM
        float hA[4], hB[4];
        #pragma unroll
        for (int j = 0; j < 4; ++j) {
            hA[j] = fmaxf(accA[j] * invA + biasq[j], 0.f);
            hB[j] = fmaxf(accB[j] * invB + biasq[j], 0.f);
        }
        float hdA[H1], hdB[H1];
        #pragma unroll
        for (int d = 0; d < H1; ++d) {
            hdA[d] = __shfl(hA[d & 3], d >> 2, 64);
            hdB[d] = __shfl(hB[d & 3], d >> 2, 64);
        }
        if (lane < C2) {
            float alA = bl2c, arA = br2c, alB = bl2c, arB = br2c;
            #pragma unroll
            for (int d = 0; d < H1; ++d) {
                alA = fmaf(hdA[d], wl2c[d], alA);
                arA = fmaf(hdA[d], wr2c[d], arA);
                alB = fmaf(hdB[d], wl2c[d], alB);
                arB = fmaf(hdB[d], wr2c[d], arB);
            }
            if (gA < NN) {
                xl2[(size_t)gA * C2 + lane] = alA;
                xr2[(size_t)gA * C2 + lane] = arA;
            }
            if (gB < NN) {
                xl2[(size_t)gB * C2 + lane] = alB;
                xr2[(size_t)gB * C2 + lane] = arB;
            }
        }
    }
}

// ---- layer-2 GAT gather (D=16): 4 nodes/wave, scalarized meta/addresses ----
__global__ __launch_bounds__(128) void k_gat2L(
        const int* __restrict__ sorted_g, const int* __restrict__ meta,
        const float* __restrict__ xl, const float* __restrict__ xr,
        const float* __restrict__ att, const float* __restrict__ bias,
        float* __restrict__ out) {
    int wv = (blockIdx.x * 128 + threadIdx.x) >> 6;
    int gbase = __builtin_amdgcn_readfirstlane(wv << 2);
    int lane = threadIdx.x & 63;
    int q = lane & 3, eo = lane >> 2;       // LPE=4, EPC=16

    float attq[4], biasq[4];
    #pragma unroll
    for (int j = 0; j < 4; ++j) { attq[j] = att[q * 4 + j]; biasq[j] = bias[q * 4 + j]; }

    #pragma unroll 2
    for (int i = 0; i < 4; ++i) {
        int g = gbase + i;
        int mt = meta[g];                   // s_load (g scalar)
        int deg = (mt & 0xFFFF) + 1;
        const int* sg = sorted_g + (size_t)(g >> 6) * CAP + (mt >> 16);

        float4 xr4 = ((const float4*)(xr + (size_t)g * C2))[q];
        float xrq[4] = {xr4.x, xr4.y, xr4.z, xr4.w};

        float denom = 0.f;
        float acc[4] = {0.f, 0.f, 0.f, 0.f};

        #pragma unroll
        for (int c = 0; c < 4; ++c) {
            if (c == 0 || deg > c * 16) {   // wave-uniform guard
                int e = c * 16 + eo;
                int src = (e > 0 && e < deg) ? sg[e - 1] : g;
                float4 v = ((const float4*)(xl + (size_t)src * C2))[q];
                float xv[4] = {v.x, v.y, v.z, v.w};
                float s = 0.f;
                #pragma unroll
                for (int j = 0; j < 4; ++j) {
                    float w = xv[j] + xrq[j];
                    w = fmaxf(w, NEG * w);
                    s = fmaf(attq[j], w, s);
                }
                s += __shfl_xor(s, 1, 64);
                s += __shfl_xor(s, 2, 64);
                float ex = (e < deg) ? __expf(s) : 0.f;
                denom += ex;
                #pragma unroll
                for (int j = 0; j < 4; ++j)
                    acc[j] = fmaf(ex, xv[j], acc[j]);
            }
        }
        for (int e0 = 64; e0 < deg; e0 += 16) {   // rare: deg > 64
            int e = e0 + eo;
            int src = (e < deg) ? sg[e - 1] : g;
            float4 v = ((const float4*)(xl + (size_t)src * C2))[q];
            float xv[4] = {v.x, v.y, v.z, v.w};
            float s = 0.f;
            #pragma unroll
            for (int j = 0; j < 4; ++j) {
                float w = xv[j] + xrq[j];
                w = fmaxf(w, NEG * w);
                s = fmaf(attq[j], w, s);
            }
            s += __shfl_xor(s, 1, 64);
            s += __shfl_xor(s, 2, 64);
            float ex = (e < deg) ? __expf(s) : 0.f;
            denom += ex;
            #pragma unroll
            for (int j = 0; j < 4; ++j)
                acc[j] = fmaf(ex, xv[j], acc[j]);
        }

        #pragma unroll
        for (int off = 4; off < 64; off <<= 1) {
            denom += __shfl_xor(denom, off, 64);
            #pragma unroll
            for (int j = 0; j < 4; ++j)
                acc[j] += __shfl_xor(acc[j], off, 64);
        }
        float inv = 1.f / denom;

        if (eo == 0) {
            float4 r;
            r.x = acc[0] * inv + biasq[0];
            r.y = acc[1] * inv + biasq[1];
            r.z = acc[2] * inv + biasq[2];
            r.w = acc[3] * inv + biasq[3];
            ((float4*)(out + (size_t)g * C2))[q] = r;
        }
    }
}

extern "C" void kernel_launch(void* const* d_in, const int* in_sizes, int n_in,
                              void* d_out, int out_size, void* d_ws, size_t ws_size,
                              hipStream_t stream) {
    const float* x     = (const float*)d_in[0];
    const int*   ei    = (const int*)d_in[1];
    const float* Wl1   = (const float*)d_in[2];
    const float* bl1   = (const float*)d_in[3];
    const float* Wr1   = (const float*)d_in[4];
    const float* br1   = (const float*)d_in[5];
    const float* att1  = (const float*)d_in[6];
    const float* bias1 = (const float*)d_in[7];
    const float* Wl2   = (const float*)d_in[8];
    const float* bl2   = (const float*)d_in[9];
    const float* Wr2   = (const float*)d_in[10];
    const float* br2   = (const float*)d_in[11];
    const float* att2  = (const float*)d_in[12];
    const float* bias2 = (const float*)d_in[13];
    float* out = (float*)d_out;

    // workspace layout
    int* bedges = (int*)d_ws;                        // NBP*CAP (sorted in-place)
    int* gcur1  = bedges + (size_t)NBP * CAP;        // 32
    int* gcur2  = gcur1 + SB;                        // NBP
    int* meta   = gcur2 + NBP;                       // NBP*64
    float* xl1  = (float*)(meta + NBP * BKT);        // NN*H1
    float* xr1  = xl1 + (size_t)NN * H1;             // NN*H1
    int* sup1   = (int*)(xr1 + (size_t)NN * H1);     // SB*SCAP (14.08 MB)
    float* xl2  = (float*)sup1;                      // overlay: sup1 dead after k_p2
    float* xr2  = xl2 + (size_t)NN * C2;             // NN*C2

    k_clr<<<4, 512, 0, stream>>>(gcur1);
    k_b<<<2605, 512, 0, stream>>>(x, Wl1, bl1, Wr1, br1, xl1, xr1,
                                  ei, gcur1, sup1);
    k_p2<<<1024, 512, 0, stream>>>(sup1, gcur1, gcur2, bedges);
    k_sortgat1<<<NB, 512, 0, stream>>>(bedges, gcur2, meta, xl1, xr1, att1, bias1,
                                       Wl2, bl2, Wr2, br2, xl2, xr2);
    k_gat2L<<<12500, 128, 0, stream>>>(bedges, meta, xl2, xr2, att2, bias2, out);
}